// Round 1
// baseline (390.038 us; speedup 1.0000x reference)
//
#include <hip/hip_runtime.h>

// ---------------------------------------------------------------------------
// Fused SAGE layer: out[m, :256] = relu?( hself[m] @ Wself + mean_n(h[neigh[m,n]]) @ Wneigh + b )
//   DIN : input feature dim (128 or 256), DOUT fixed = 256
//   F   : fanout
//   RM  : rows per thread; block handles TM = 8*RM dst rows with 256 threads
// ---------------------------------------------------------------------------
template<int DIN, int F, int RM, bool RELU>
__global__ __launch_bounds__(256)
void sage_layer(const float* __restrict__ h_in,
                const int*   __restrict__ neigh,
                const float* __restrict__ Wself,
                const float* __restrict__ Wneigh,
                const float* __restrict__ bias,
                float* __restrict__ h_out)
{
    constexpr int TM     = 8 * RM;
    constexpr int ROWLEN = 2 * DIN + 4;   // +4 floats pad, keeps float4 alignment
    constexpr int QD     = DIN / 4;

    __shared__ float hst[TM][ROWLEN];     // [m][0..DIN) = self, [m][DIN..2*DIN) = mean(neigh)
    __shared__ int   nb[TM * F];

    const int  tid = threadIdx.x;
    const long r0  = (long)blockIdx.x * TM;

    // neighbor indices -> LDS
    for (int p = tid; p < TM * F; p += 256)
        nb[p] = neigh[r0 * F + p];

    // stage self rows (coalesced float4, conflict-free row-major LDS writes)
    for (int p = tid; p < TM * QD; p += 256) {
        int m = p / QD, q = p - m * QD;
        float4 v = reinterpret_cast<const float4*>(h_in + (r0 + m) * DIN)[q];
        *reinterpret_cast<float4*>(&hst[m][q * 4]) = v;
    }
    __syncthreads();   // nb ready

    // gather + mean of neighbors
    constexpr float invF = 1.0f / F;
    for (int p = tid; p < TM * QD; p += 256) {
        int m = p / QD, q = p - m * QD;
        float4 a = make_float4(0.f, 0.f, 0.f, 0.f);
        #pragma unroll
        for (int n = 0; n < F; ++n) {
            long idx = nb[m * F + n];
            float4 v = reinterpret_cast<const float4*>(h_in + idx * DIN)[q];
            a.x += v.x; a.y += v.y; a.z += v.z; a.w += v.w;
        }
        a.x *= invF; a.y *= invF; a.z *= invF; a.w *= invF;
        *reinterpret_cast<float4*>(&hst[m][DIN + q * 4]) = a;
    }
    __syncthreads();

    // GEMM phase: thread -> RM rows x 8 cols. h from LDS (broadcast), W streamed from L2.
    const int nt = tid & 31;
    const int mt = tid >> 5;
    const int c0 = nt * 8;
    const int m0 = mt * RM;

    float bs[8];
    #pragma unroll
    for (int j = 0; j < 8; ++j) bs[j] = bias[c0 + j];

    float acc[RM][8];
    #pragma unroll
    for (int i = 0; i < RM; ++i)
        #pragma unroll
        for (int j = 0; j < 8; ++j) acc[i][j] = 0.f;

    for (int k4 = 0; k4 < DIN; k4 += 4) {
        float hsv[RM][4], hnv[RM][4];
        #pragma unroll
        for (int i = 0; i < RM; ++i) {
            float4 t = *reinterpret_cast<const float4*>(&hst[m0 + i][k4]);
            hsv[i][0] = t.x; hsv[i][1] = t.y; hsv[i][2] = t.z; hsv[i][3] = t.w;
            float4 u = *reinterpret_cast<const float4*>(&hst[m0 + i][DIN + k4]);
            hnv[i][0] = u.x; hnv[i][1] = u.y; hnv[i][2] = u.z; hnv[i][3] = u.w;
        }
        #pragma unroll
        for (int kk = 0; kk < 4; ++kk) {
            const float4* wsp = reinterpret_cast<const float4*>(Wself  + (k4 + kk) * 256 + c0);
            const float4* wnp = reinterpret_cast<const float4*>(Wneigh + (k4 + kk) * 256 + c0);
            float4 ws0 = wsp[0], ws1 = wsp[1];
            float4 wn0 = wnp[0], wn1 = wnp[1];
            float wsv[8] = {ws0.x, ws0.y, ws0.z, ws0.w, ws1.x, ws1.y, ws1.z, ws1.w};
            float wnv[8] = {wn0.x, wn0.y, wn0.z, wn0.w, wn1.x, wn1.y, wn1.z, wn1.w};
            #pragma unroll
            for (int i = 0; i < RM; ++i) {
                float a = hsv[i][kk];
                float b = hnv[i][kk];
                #pragma unroll
                for (int j = 0; j < 8; ++j)
                    acc[i][j] += a * wsv[j] + b * wnv[j];
            }
        }
    }

    // epilogue: bias (+relu), coalesced float4 stores
    #pragma unroll
    for (int i = 0; i < RM; ++i) {
        float o[8];
        #pragma unroll
        for (int j = 0; j < 8; ++j) {
            float v = acc[i][j] + bs[j];
            if (RELU) v = fmaxf(v, 0.f);
            o[j] = v;
        }
        float4* dst = reinterpret_cast<float4*>(h_out + (r0 + m0 + i) * 256 + c0);
        dst[0] = make_float4(o[0], o[1], o[2], o[3]);
        dst[1] = make_float4(o[4], o[5], o[6], o[7]);
    }
}

// ---------------------------------------------------------------------------
// Final layer: M=1024, DIN=256, F=5, DOUT=47, no relu. One block (64 thr) per row.
// ---------------------------------------------------------------------------
__global__ __launch_bounds__(64)
void sage_out(const float* __restrict__ h_in,
              const int*   __restrict__ neigh,
              const float* __restrict__ Wself,
              const float* __restrict__ Wneigh,
              const float* __restrict__ bias,
              float* __restrict__ out)
{
    __shared__ float hs[256], hn[256];
    __shared__ int   nb[5];
    const int r = blockIdx.x, tid = threadIdx.x;

    if (tid < 5) nb[tid] = neigh[r * 5 + tid];
    __syncthreads();

    for (int k = tid; k < 256; k += 64) {
        hs[k] = h_in[(long)r * 256 + k];
        float a = 0.f;
        #pragma unroll
        for (int n = 0; n < 5; ++n) a += h_in[(long)nb[n] * 256 + k];
        hn[k] = a * 0.2f;
    }
    __syncthreads();

    if (tid < 47) {
        float acc = bias[tid];
        for (int k = 0; k < 256; ++k)
            acc += hs[k] * Wself[k * 47 + tid] + hn[k] * Wneigh[k * 47 + tid];
        out[r * 47 + tid] = acc;
    }
}

// ---------------------------------------------------------------------------
extern "C" void kernel_launch(void* const* d_in, const int* in_sizes, int n_in,
                              void* d_out, int out_size, void* d_ws, size_t ws_size,
                              hipStream_t stream)
{
    const float* x   = (const float*)d_in[0];
    const int*   n0  = (const int*)  d_in[1];
    const int*   n1  = (const int*)  d_in[2];
    const int*   n2  = (const int*)  d_in[3];
    const float* Ws0 = (const float*)d_in[4];
    const float* Wn0 = (const float*)d_in[5];
    const float* b0  = (const float*)d_in[6];
    const float* Ws1 = (const float*)d_in[7];
    const float* Wn1 = (const float*)d_in[8];
    const float* b1  = (const float*)d_in[9];
    const float* Ws2 = (const float*)d_in[10];
    const float* Wn2 = (const float*)d_in[11];
    const float* b2  = (const float*)d_in[12];
    float* out = (float*)d_out;

    float* h1 = (float*)d_ws;                       // 67584 x 256 fp32 = 69.2 MB
    float* h2 = h1 + (size_t)67584 * 256;           //  6144 x 256 fp32 =  6.3 MB

    // layer 0: 67584 rows, TM=32 -> 2112 blocks
    sage_layer<128, 15, 4, true ><<<67584 / 32, 256, 0, stream>>>(x,  n0, Ws0, Wn0, b0, h1);
    // layer 1: 6144 rows, TM=24 -> 256 blocks (LDS 24*516*4 = 49.5 KB < 64 KB static limit)
    sage_layer<256, 10, 3, true ><<<6144  / 24, 256, 0, stream>>>(h1, n1, Ws1, Wn1, b1, h2);
    // layer 2: 1024 rows
    sage_out<<<1024, 64, 0, stream>>>(h2, n2, Ws2, Wn2, b2, out);
}

// Round 2
// 192.927 us; speedup vs baseline: 2.0217x; 2.0217x over previous
//
#include <hip/hip_runtime.h>

using bf16x8 = __attribute__((ext_vector_type(8))) short;
using f32x4  = __attribute__((ext_vector_type(4))) float;

// ---- bf16 helpers (RNE) ----------------------------------------------------
__device__ __forceinline__ short f2bf(float x) {
    union { float f; unsigned u; } v; v.f = x;
    unsigned r = v.u + 0x7fffu + ((v.u >> 16) & 1u);
    return (short)(r >> 16);
}
__device__ __forceinline__ float bf2f(short h) {
    union { unsigned u; float f; } v; v.u = ((unsigned)(unsigned short)h) << 16;
    return v.f;
}

// ---------------------------------------------------------------------------
// Pack Wself/Wneigh (fp32, [DIN][256] each) into MFMA B-fragment order,
// split hi/lo bf16.  Ktot = 2*DIN (self rows then neigh rows).
// Layout: for blk = ks*16+nt (ks over Ktot/32, nt over 16):
//   Wp[blk*1024 + lane*8 .. +8]        = hi frag (8 bf16)
//   Wp[blk*1024 + 512 + lane*8 .. +8]  = lo frag
// B-frag mapping: lane holds B[k = ks*32 + (lane>>4)*8 + e][n = nt*16 + (lane&15)]
// ---------------------------------------------------------------------------
template<int DIN>
__global__ __launch_bounds__(64)
void pack_w(const float* __restrict__ Wself, const float* __restrict__ Wneigh,
            short* __restrict__ Wp)
{
    const int blk = blockIdx.x;            // ks*16 + nt
    const int ks  = blk >> 4, nt = blk & 15;
    const int l   = threadIdx.x;
    const int col = nt * 16 + (l & 15);
    const int k0  = ks * 32 + (l >> 4) * 8;

    bf16x8 hi, lo;
    #pragma unroll
    for (int e = 0; e < 8; ++e) {
        int k = k0 + e;
        float w = (k < DIN) ? Wself[k * 256 + col] : Wneigh[(k - DIN) * 256 + col];
        short h = f2bf(w);
        hi[e] = h;
        lo[e] = f2bf(w - bf2f(h));
    }
    *reinterpret_cast<bf16x8*>(Wp + (size_t)blk * 1024 + l * 8)       = hi;
    *reinterpret_cast<bf16x8*>(Wp + (size_t)blk * 1024 + 512 + l * 8) = lo;
}

// ---------------------------------------------------------------------------
// Fused SAGE layer with split-precision bf16 MFMA.
//   out[m] = relu?( [h_self | mean_neigh] @ Wcat + b ),  DOUT = 256
//   Each wave: 16 rows x (NTW*16) cols.  mfma_f32_16x16x32_bf16, 3-term split.
//   RB = rows per block.  If NTW<16 all waves share rows, split nt-range;
//   else each wave owns its own 16-row strip.
// ---------------------------------------------------------------------------
template<int DIN, int F, int WAVES, int RB, int NTW, bool RELU>
__global__ __launch_bounds__(WAVES * 64)
void sage_mfma(const float* __restrict__ h_in,
               const int*   __restrict__ neigh,
               const short* __restrict__ Wp,
               const float* __restrict__ bias,
               float* __restrict__ h_out)
{
    constexpr int KS   = DIN / 16;      // k-steps over Ktot=2*DIN (32 each)
    constexpr int KSH  = DIN / 32;      // self k-steps
    constexpr int QD   = DIN / 4;       // float4 chunks per row
    constexpr int LROW = DIN + 4;       // fp32 row stride (16B pad, bank-skewed)

    __shared__ float An[RB][LROW];      // mean of neighbor rows (fp32)
    __shared__ int   nb[RB * F];

    const int tid = threadIdx.x;
    const long r0 = (long)blockIdx.x * RB;

    for (int p = tid; p < RB * F; p += WAVES * 64)
        nb[p] = neigh[r0 * F + p];
    __syncthreads();

    constexpr float invF = 1.0f / F;
    for (int p = tid; p < RB * QD; p += WAVES * 64) {
        int m = p / QD, q = p - m * QD;
        float4 a = make_float4(0.f, 0.f, 0.f, 0.f);
        #pragma unroll
        for (int n = 0; n < F; ++n) {
            long idx = nb[m * F + n];
            float4 v = reinterpret_cast<const float4*>(h_in + idx * DIN)[q];
            a.x += v.x; a.y += v.y; a.z += v.z; a.w += v.w;
        }
        a.x *= invF; a.y *= invF; a.z *= invF; a.w *= invF;
        *reinterpret_cast<float4*>(&An[m][q * 4]) = a;
    }
    __syncthreads();

    const int w  = tid >> 6;
    const int l  = tid & 63;
    const int lr = l & 15;              // A-frag row / C col
    const int lk = l >> 4;              // A-frag k-group / C row-group
    constexpr bool SPLIT_NT = (NTW < 16);
    const int wrow = SPLIT_NT ? 0 : w * 16;
    const int nt0  = SPLIT_NT ? w * NTW : 0;

    const float* selfrow  = h_in + (r0 + wrow + lr) * DIN;
    const float* neighrow = &An[wrow + lr][0];

    f32x4 acc[NTW];
    #pragma unroll
    for (int j = 0; j < NTW; ++j) acc[j] = f32x4{0.f, 0.f, 0.f, 0.f};

    for (int ks = 0; ks < KS; ++ks) {
        // ---- A fragment: 8 fp32 -> split bf16 hi/lo ----
        float v[8];
        if (ks < KSH) {
            const int k0 = ks * 32 + lk * 8;
            float4 t0 = *reinterpret_cast<const float4*>(selfrow + k0);
            float4 t1 = *reinterpret_cast<const float4*>(selfrow + k0 + 4);
            v[0]=t0.x; v[1]=t0.y; v[2]=t0.z; v[3]=t0.w;
            v[4]=t1.x; v[5]=t1.y; v[6]=t1.z; v[7]=t1.w;
        } else {
            const int k0 = (ks - KSH) * 32 + lk * 8;
            float4 t0 = *reinterpret_cast<const float4*>(neighrow + k0);
            float4 t1 = *reinterpret_cast<const float4*>(neighrow + k0 + 4);
            v[0]=t0.x; v[1]=t0.y; v[2]=t0.z; v[3]=t0.w;
            v[4]=t1.x; v[5]=t1.y; v[6]=t1.z; v[7]=t1.w;
        }
        bf16x8 ah, al;
        #pragma unroll
        for (int e = 0; e < 8; ++e) {
            short h = f2bf(v[e]);
            ah[e] = h;
            al[e] = f2bf(v[e] - bf2f(h));
        }

        // ---- B fragments streamed from packed W; 3-term split MFMA ----
        const bf16x8* wp = reinterpret_cast<const bf16x8*>(Wp) +
                           (size_t)(ks * 16 + nt0) * 128;
        #pragma unroll
        for (int j = 0; j < NTW; ++j) {
            bf16x8 bh = wp[j * 128 + l];
            bf16x8 bl = wp[j * 128 + 64 + l];
            acc[j] = __builtin_amdgcn_mfma_f32_16x16x32_bf16(ah, bh, acc[j], 0, 0, 0);
            acc[j] = __builtin_amdgcn_mfma_f32_16x16x32_bf16(al, bh, acc[j], 0, 0, 0);
            acc[j] = __builtin_amdgcn_mfma_f32_16x16x32_bf16(ah, bl, acc[j], 0, 0, 0);
        }
    }

    // ---- epilogue: bias (+relu), C/D layout col=lane&15, row=(lane>>4)*4+r ----
    #pragma unroll
    for (int j = 0; j < NTW; ++j) {
        const int col = (nt0 + j) * 16 + lr;
        const float b = bias[col];
        #pragma unroll
        for (int r = 0; r < 4; ++r) {
            const int row = wrow + lk * 4 + r;
            float val = acc[j][r] + b;
            if (RELU) val = fmaxf(val, 0.f);
            h_out[(r0 + row) * 256 + col] = val;
        }
    }
}

// ---------------------------------------------------------------------------
// Final layer: M=1024, DIN=256, F=5, DOUT=47, fp32 vector math (tiny).
// ---------------------------------------------------------------------------
__global__ __launch_bounds__(64)
void sage_out(const float* __restrict__ h_in,
              const int*   __restrict__ neigh,
              const float* __restrict__ Wself,
              const float* __restrict__ Wneigh,
              const float* __restrict__ bias,
              float* __restrict__ out)
{
    __shared__ float hs[256], hn[256];
    __shared__ int   nb[5];
    const int r = blockIdx.x, tid = threadIdx.x;

    if (tid < 5) nb[tid] = neigh[r * 5 + tid];
    __syncthreads();

    for (int k = tid; k < 256; k += 64) {
        hs[k] = h_in[(long)r * 256 + k];
        float a = 0.f;
        #pragma unroll
        for (int n = 0; n < 5; ++n) a += h_in[(long)nb[n] * 256 + k];
        hn[k] = a * 0.2f;
    }
    __syncthreads();

    if (tid < 47) {
        float acc = bias[tid];
        for (int k = 0; k < 256; ++k)
            acc += hs[k] * Wself[k * 47 + tid] + hn[k] * Wneigh[k * 47 + tid];
        out[r * 47 + tid] = acc;
    }
}

// ---------------------------------------------------------------------------
extern "C" void kernel_launch(void* const* d_in, const int* in_sizes, int n_in,
                              void* d_out, int out_size, void* d_ws, size_t ws_size,
                              hipStream_t stream)
{
    const float* x   = (const float*)d_in[0];
    const int*   n0  = (const int*)  d_in[1];
    const int*   n1  = (const int*)  d_in[2];
    const int*   n2  = (const int*)  d_in[3];
    const float* Ws0 = (const float*)d_in[4];
    const float* Wn0 = (const float*)d_in[5];
    const float* b0  = (const float*)d_in[6];
    const float* Ws1 = (const float*)d_in[7];
    const float* Wn1 = (const float*)d_in[8];
    const float* b1  = (const float*)d_in[9];
    const float* Ws2 = (const float*)d_in[10];
    const float* Wn2 = (const float*)d_in[11];
    const float* b2  = (const float*)d_in[12];
    float* out = (float*)d_out;

    // workspace layout
    float* h1  = (float*)d_ws;                           // 67584*256 f32 = 69.2 MB
    float* h2  = h1 + (size_t)67584 * 256;               //  6144*256 f32 =  6.3 MB
    short* Wp0 = (short*)(h2 + (size_t)6144 * 256);      // 8*16*1024 bf16 = 256 KB
    short* Wp1 = Wp0 + (size_t)8 * 16 * 1024;            // 16*16*1024 bf16 = 512 KB

    // pack weights (split hi/lo bf16, B-fragment order)
    pack_w<128><<<8 * 16,  64, 0, stream>>>(Ws0, Wn0, Wp0);
    pack_w<256><<<16 * 16, 64, 0, stream>>>(Ws1, Wn1, Wp1);

    // layer 0: 67584 rows, RB=64 (4 waves x 16 rows, each all 16 nt) -> 1056 blocks
    sage_mfma<128, 15, 4, 64, 16, true><<<67584 / 64, 256, 0, stream>>>(x,  n0, Wp0, b0, h1);
    // layer 1: 6144 rows, RB=16 shared by 4 waves, nt split 4 each -> 384 blocks
    sage_mfma<256, 10, 4, 16, 4,  true><<<6144 / 16,  256, 0, stream>>>(h1, n1, Wp1, b1, h2);
    // layer 2
    sage_out<<<1024, 64, 0, stream>>>(h2, n2, Ws2, Wn2, b2, out);
}

// Round 4
// 187.972 us; speedup vs baseline: 2.0750x; 1.0264x over previous
//
#include <hip/hip_runtime.h>

using bf16x8 = __attribute__((ext_vector_type(8))) short;
using f32x4  = __attribute__((ext_vector_type(4))) float;

// ---- bf16 helpers (RNE) ----------------------------------------------------
__device__ __forceinline__ short f2bf(float x) {
    union { float f; unsigned u; } v; v.f = x;
    unsigned r = v.u + 0x7fffu + ((v.u >> 16) & 1u);
    return (short)(r >> 16);
}
__device__ __forceinline__ float bf2f(short h) {
    union { unsigned u; float f; } v; v.u = ((unsigned)(unsigned short)h) << 16;
    return v.f;
}

// ---------------------------------------------------------------------------
// Pack Wself/Wneigh (fp32, [DIN][256] each) into MFMA B-fragment order,
// split hi/lo bf16.  Ktot = 2*DIN (self rows then neigh rows).
// blk = ks*16+nt:  Wp[blk*1024 + l*8]=hi frag,  Wp[blk*1024 + 512 + l*8]=lo.
// B-frag: lane l holds B[k = ks*32 + (l>>4)*8 + e][n = nt*16 + (l&15)]
// ---------------------------------------------------------------------------
template<int DIN>
__global__ __launch_bounds__(64)
void pack_w(const float* __restrict__ Wself, const float* __restrict__ Wneigh,
            short* __restrict__ Wp)
{
    const int blk = blockIdx.x;
    const int ks  = blk >> 4, nt = blk & 15;
    const int l   = threadIdx.x;
    const int col = nt * 16 + (l & 15);
    const int k0  = ks * 32 + (l >> 4) * 8;

    bf16x8 hi, lo;
    #pragma unroll
    for (int e = 0; e < 8; ++e) {
        int k = k0 + e;
        float w = (k < DIN) ? Wself[k * 256 + col] : Wneigh[(k - DIN) * 256 + col];
        short h = f2bf(w);
        hi[e] = h;
        lo[e] = f2bf(w - bf2f(h));
    }
    *reinterpret_cast<bf16x8*>(Wp + (size_t)blk * 1024 + l * 8)       = hi;
    *reinterpret_cast<bf16x8*>(Wp + (size_t)blk * 1024 + 512 + l * 8) = lo;
}

// ---------------------------------------------------------------------------
// Fused SAGE layer, split-precision bf16 MFMA (16x16x32), DOUT = 256.
// Control flow identical to the R2 kernel that passed post-timing validation:
//   nb -> barrier -> gather-mean into LDS -> barrier -> single k-loop GEMM
// with self rows read from global INSIDE the k-loop (no prefetch reordering).
//   IN_BF16:  input features are bf16 (exact -> 2-term self MFMA)
//   OUT_BF16: write output as bf16
// ---------------------------------------------------------------------------
template<int DIN, int F, int RB, int NTW, bool IN_BF16, bool OUT_BF16, bool RELU>
__global__ __launch_bounds__(256)
void sage_mfma(const void* __restrict__ h_in_v,
               const int*   __restrict__ neigh,
               const short* __restrict__ Wp,
               const float* __restrict__ bias,
               void* __restrict__ h_out_v)
{
    constexpr int KS   = DIN / 16;          // k-steps over Ktot = 2*DIN (32 each)
    constexpr int KSH  = DIN / 32;          // self-half k-steps
    constexpr int LROW = DIN + 4;
    constexpr bool SPLIT_NT = (NTW < 16);
    constexpr float invF = 1.0f / F;

    __shared__ float An[RB][LROW];          // mean of neighbor rows (fp32)
    __shared__ int   nb[RB * F];

    const int  tid = threadIdx.x;
    const int  w   = tid >> 6, l = tid & 63;
    const int  lr  = l & 15, lk = l >> 4;
    const long r0  = (long)blockIdx.x * RB;
    const int  wrow = SPLIT_NT ? 0 : w * 16;
    const int  nt0  = SPLIT_NT ? w * NTW : 0;

    for (int p = tid; p < RB * F; p += 256)
        nb[p] = neigh[r0 * F + p];
    __syncthreads();                        // nb ready

    if constexpr (!IN_BF16) {
        // ---- gather + mean (fp32 rows) ----
        constexpr int QD = DIN / 4;
        const float* hin = (const float*)h_in_v;
        for (int p = tid; p < RB * QD; p += 256) {
            int m = p / QD, q = p - m * QD;
            float4 a = make_float4(0.f, 0.f, 0.f, 0.f);
            #pragma unroll
            for (int n = 0; n < F; ++n) {
                long idx = nb[m * F + n];
                float4 v = reinterpret_cast<const float4*>(hin + idx * DIN)[q];
                a.x += v.x; a.y += v.y; a.z += v.z; a.w += v.w;
            }
            a.x *= invF; a.y *= invF; a.z *= invF; a.w *= invF;
            *reinterpret_cast<float4*>(&An[m][q * 4]) = a;
        }
    } else {
        // ---- gather + mean (bf16 rows, fp32 accumulate) ----
        constexpr int NQ = DIN / 8;
        const short* hin = (const short*)h_in_v;
        for (int p = tid; p < RB * NQ; p += 256) {
            int m = p / NQ, c = p - m * NQ;
            float a[8] = {0.f,0.f,0.f,0.f,0.f,0.f,0.f,0.f};
            #pragma unroll
            for (int n = 0; n < F; ++n) {
                long idx = nb[m * F + n];
                bf16x8 v = *reinterpret_cast<const bf16x8*>(hin + idx * DIN + c * 8);
                #pragma unroll
                for (int e = 0; e < 8; ++e) a[e] += bf2f(v[e]);
            }
            #pragma unroll
            for (int e = 0; e < 8; ++e) a[e] *= invF;
            *reinterpret_cast<float4*>(&An[m][c * 8])     = make_float4(a[0],a[1],a[2],a[3]);
            *reinterpret_cast<float4*>(&An[m][c * 8 + 4]) = make_float4(a[4],a[5],a[6],a[7]);
        }
    }
    __syncthreads();                        // An ready

    // ---- GEMM: single k-loop, self half from global, neigh half from LDS ----
    const float* selfrowF = (const float*)h_in_v + (r0 + wrow + lr) * DIN;
    const short* selfrowB = (const short*)h_in_v + (r0 + wrow + lr) * DIN;
    const float* neighrow = &An[wrow + lr][0];

    f32x4 acc[NTW];
    #pragma unroll
    for (int j = 0; j < NTW; ++j) acc[j] = f32x4{0.f, 0.f, 0.f, 0.f};

    for (int ks = 0; ks < KS; ++ks) {
        bf16x8 ah, al;
        bool self_exact = false;
        if (ks < KSH) {
            if constexpr (IN_BF16) {
                ah = *reinterpret_cast<const bf16x8*>(selfrowB + ks * 32 + lk * 8);
                self_exact = true;
            } else {
                const int k0 = ks * 32 + lk * 8;
                float4 t0 = *reinterpret_cast<const float4*>(selfrowF + k0);
                float4 t1 = *reinterpret_cast<const float4*>(selfrowF + k0 + 4);
                float v[8] = {t0.x, t0.y, t0.z, t0.w, t1.x, t1.y, t1.z, t1.w};
                #pragma unroll
                for (int e = 0; e < 8; ++e) {
                    short h = f2bf(v[e]);
                    ah[e] = h;
                    al[e] = f2bf(v[e] - bf2f(h));
                }
            }
        } else {
            const int k0 = (ks - KSH) * 32 + lk * 8;
            float4 t0 = *reinterpret_cast<const float4*>(neighrow + k0);
            float4 t1 = *reinterpret_cast<const float4*>(neighrow + k0 + 4);
            float v[8] = {t0.x, t0.y, t0.z, t0.w, t1.x, t1.y, t1.z, t1.w};
            #pragma unroll
            for (int e = 0; e < 8; ++e) {
                short h = f2bf(v[e]);
                ah[e] = h;
                al[e] = f2bf(v[e] - bf2f(h));
            }
        }

        const bf16x8* wp = reinterpret_cast<const bf16x8*>(Wp) +
                           (size_t)(ks * 16 + nt0) * 128;
        #pragma unroll
        for (int j = 0; j < NTW; ++j) {
            bf16x8 bh = wp[j * 128 + l];
            bf16x8 bl = wp[j * 128 + 64 + l];
            acc[j] = __builtin_amdgcn_mfma_f32_16x16x32_bf16(ah, bh, acc[j], 0, 0, 0);
            if (!self_exact)
                acc[j] = __builtin_amdgcn_mfma_f32_16x16x32_bf16(al, bh, acc[j], 0, 0, 0);
            acc[j] = __builtin_amdgcn_mfma_f32_16x16x32_bf16(ah, bl, acc[j], 0, 0, 0);
        }
    }

    // ---- epilogue: bias (+relu); C/D: col=l&15, row=(l>>4)*4+r ----
    #pragma unroll
    for (int j = 0; j < NTW; ++j) {
        const int col = (nt0 + j) * 16 + lr;
        const float b = bias[col];
        #pragma unroll
        for (int r = 0; r < 4; ++r) {
            const long row = r0 + wrow + lk * 4 + r;
            float val = acc[j][r] + b;
            if (RELU) val = fmaxf(val, 0.f);
            if constexpr (OUT_BF16)
                ((short*)h_out_v)[row * 256 + col] = f2bf(val);
            else
                ((float*)h_out_v)[row * 256 + col] = val;
        }
    }
}

// ---------------------------------------------------------------------------
// Final layer: M=1024, DIN=256, F=5, DOUT=47, fp32 vector math (tiny).
// ---------------------------------------------------------------------------
__global__ __launch_bounds__(64)
void sage_out(const float* __restrict__ h_in,
              const int*   __restrict__ neigh,
              const float* __restrict__ Wself,
              const float* __restrict__ Wneigh,
              const float* __restrict__ bias,
              float* __restrict__ out)
{
    __shared__ float hs[256], hn[256];
    __shared__ int   nb[5];
    const int r = blockIdx.x, tid = threadIdx.x;

    if (tid < 5) nb[tid] = neigh[r * 5 + tid];
    __syncthreads();

    for (int k = tid; k < 256; k += 64) {
        hs[k] = h_in[(long)r * 256 + k];
        float a = 0.f;
        #pragma unroll
        for (int n = 0; n < 5; ++n) a += h_in[(long)nb[n] * 256 + k];
        hn[k] = a * 0.2f;
    }
    __syncthreads();

    if (tid < 47) {
        float acc = bias[tid];
        for (int k = 0; k < 256; ++k)
            acc += hs[k] * Wself[k * 47 + tid] + hn[k] * Wneigh[k * 47 + tid];
        out[r * 47 + tid] = acc;
    }
}

// ---------------------------------------------------------------------------
extern "C" void kernel_launch(void* const* d_in, const int* in_sizes, int n_in,
                              void* d_out, int out_size, void* d_ws, size_t ws_size,
                              hipStream_t stream)
{
    const float* x   = (const float*)d_in[0];
    const int*   n0  = (const int*)  d_in[1];
    const int*   n1  = (const int*)  d_in[2];
    const int*   n2  = (const int*)  d_in[3];
    const float* Ws0 = (const float*)d_in[4];
    const float* Wn0 = (const float*)d_in[5];
    const float* b0  = (const float*)d_in[6];
    const float* Ws1 = (const float*)d_in[7];
    const float* Wn1 = (const float*)d_in[8];
    const float* b1  = (const float*)d_in[9];
    const float* Ws2 = (const float*)d_in[10];
    const float* Wn2 = (const float*)d_in[11];
    const float* b2  = (const float*)d_in[12];
    float* out = (float*)d_out;

    // workspace layout
    short* h1  = (short*)d_ws;                            // 67584*256 bf16 = 34.6 MB
    float* h2  = (float*)(h1 + (size_t)67584 * 256);      //  6144*256 f32  =  6.3 MB
    short* Wp0 = (short*)(h2 + (size_t)6144 * 256);       //  8*16*1024 bf16 = 256 KB
    short* Wp1 = Wp0 + (size_t)8 * 16 * 1024;             // 16*16*1024 bf16 = 512 KB

    pack_w<128><<<8 * 16,  64, 0, stream>>>(Ws0, Wn0, Wp0);
    pack_w<256><<<16 * 16, 64, 0, stream>>>(Ws1, Wn1, Wp1);

    // layer 0: fp32 in, bf16 out; RB=64 (4 waves x 16-row strips, all 16 nt)
    sage_mfma<128, 15, 64, 16, false, true,  true><<<67584 / 64, 256, 0, stream>>>(x,  n0, Wp0, b0, h1);
    // layer 1: bf16 in, fp32 out; RB=16 shared rows, nt split 4/wave
    sage_mfma<256, 10, 16, 4,  true,  false, true><<<6144 / 16,  256, 0, stream>>>(h1, n1, Wp1, b1, h2);
    // layer 2
    sage_out<<<1024, 64, 0, stream>>>(h2, n2, Ws2, Wn2, b2, out);
}